// Round 2
// baseline (756.535 us; speedup 1.0000x reference)
//
#include <hip/hip_runtime.h>
#include <math.h>

#define XROWS 12544      // 256*49
#define YROWS 2048       // 64*32
#define HD 512
#define NM 49
#define NL 32
#define MP1 50
#define LP1 33
#define BSTRIDE 1650     // (m+1)*(L+1)
#define NEGV -1000000.0f
#define REGV 0.1f
#define INVREG 10.0f

// ---------------------------------------------------------------- norms
__global__ __launch_bounds__(256) void norm_kernel(
    const float* __restrict__ x, const float* __restrict__ y,
    float* __restrict__ invx, float* __restrict__ invy)
{
    int wid = blockIdx.x * 4 + (threadIdx.x >> 6);
    int lane = threadIdx.x & 63;
    if (wid >= XROWS + YROWS) return;
    const float* src;
    float* dst;
    if (wid < XROWS) { src = x + (size_t)wid * HD;           dst = invx + wid; }
    else             { src = y + (size_t)(wid - XROWS) * HD; dst = invy + (wid - XROWS); }
    float4 v0 = *(const float4*)(src + lane * 8);
    float4 v1 = *(const float4*)(src + lane * 8 + 4);
    float s = v0.x*v0.x + v0.y*v0.y + v0.z*v0.z + v0.w*v0.w
            + v1.x*v1.x + v1.y*v1.y + v1.z*v1.z + v1.w*v1.w;
    #pragma unroll
    for (int o = 32; o > 0; o >>= 1) s += __shfl_xor(s, o, 64);
    if (lane == 0) *dst = 1.0f / fmaxf(sqrtf(s), 1e-12f);
}

// ---------------------------------------------------------------- scores GEMM
// C[12544 x 2048] = Xn * Yn^T, written into d_out at ((i*64+j)*1650 + p*32 + l)
__global__ __launch_bounds__(256) void gemm_kernel(
    const float* __restrict__ x, const float* __restrict__ y,
    const float* __restrict__ invx, const float* __restrict__ invy,
    float* __restrict__ outS)
{
    __shared__ float sA[16 * 132];
    __shared__ float sB[16 * 132];
    const int mblk = blockIdx.x >> 4;      // 0..97
    const int nblk = blockIdx.x & 15;      // 0..15 (fastest -> A-tile L2 reuse)
    const int m0 = mblk * 128, n0 = nblk * 128;
    const int tid = threadIdx.x;
    const int tr = tid >> 4, tc = tid & 15;
    float acc[8][8];
    #pragma unroll
    for (int a = 0; a < 8; ++a)
        #pragma unroll
        for (int b2 = 0; b2 < 8; ++b2) acc[a][b2] = 0.f;

    for (int kc = 0; kc < 32; ++kc) {
        const int k0 = kc * 16;
        #pragma unroll
        for (int t = tid; t < 512; t += 256) {
            const int r = t >> 2;
            const int kg = (t & 3) << 2;
            float4 va = *(const float4*)(x + (size_t)(m0 + r) * HD + k0 + kg);
            const float ia = invx[m0 + r];
            sA[(kg + 0) * 132 + r] = va.x * ia;
            sA[(kg + 1) * 132 + r] = va.y * ia;
            sA[(kg + 2) * 132 + r] = va.z * ia;
            sA[(kg + 3) * 132 + r] = va.w * ia;
            float4 vb = *(const float4*)(y + (size_t)(n0 + r) * HD + k0 + kg);
            const float ib = invy[n0 + r];
            sB[(kg + 0) * 132 + r] = vb.x * ib;
            sB[(kg + 1) * 132 + r] = vb.y * ib;
            sB[(kg + 2) * 132 + r] = vb.z * ib;
            sB[(kg + 3) * 132 + r] = vb.w * ib;
        }
        __syncthreads();
        #pragma unroll
        for (int kk = 0; kk < 16; ++kk) {
            const float4 a0 = *(const float4*)&sA[kk * 132 + tr * 8];
            const float4 a1 = *(const float4*)&sA[kk * 132 + tr * 8 + 4];
            const float4 b0 = *(const float4*)&sB[kk * 132 + tc * 8];
            const float4 b1 = *(const float4*)&sB[kk * 132 + tc * 8 + 4];
            const float av[8] = {a0.x, a0.y, a0.z, a0.w, a1.x, a1.y, a1.z, a1.w};
            const float bv[8] = {b0.x, b0.y, b0.z, b0.w, b1.x, b1.y, b1.z, b1.w};
            #pragma unroll
            for (int uu = 0; uu < 8; ++uu)
                #pragma unroll
                for (int vv = 0; vv < 8; ++vv)
                    acc[uu][vv] = fmaf(av[uu], bv[vv], acc[uu][vv]);
        }
        __syncthreads();
    }
    #pragma unroll
    for (int uu = 0; uu < 8; ++uu) {
        const int r = m0 + tr * 8 + uu;
        const int i = r / NM;
        const int p = r - i * NM;
        const int c0 = n0 + tc * 8;
        const int j = c0 >> 5;
        const int l0 = c0 & 31;
        float* dst = outS + (size_t)(i * 64 + j) * BSTRIDE + p * 32 + l0;
        *(float2*)(dst + 0) = make_float2(acc[uu][0], acc[uu][1]);
        *(float2*)(dst + 2) = make_float2(acc[uu][2], acc[uu][3]);
        *(float2*)(dst + 4) = make_float2(acc[uu][4], acc[uu][5]);
        *(float2*)(dst + 6) = make_float2(acc[uu][6], acc[uu][7]);
    }
}

// ---------------------------------------------------------------- sinkhorn per pair
__global__ __launch_bounds__(256) void sinkhorn_kernel(
    float* __restrict__ outZ,
    const int* __restrict__ ymask,
    const float* __restrict__ d_im, const float* __restrict__ d_lang,
    float* __restrict__ scores2)
{
    const int b = blockIdx.x;
    const int j = b & 63;
    const int tid = threadIdx.x;
    __shared__ float sC[MP1 * LP1];
    __shared__ float su[MP1];
    __shared__ float sv[LP1];
    __shared__ float cmask[LP1];
    __shared__ float meta[4];
    __shared__ float wred[4];
    float* base = outZ + (size_t)b * BSTRIDE;

    if (tid < LP1)
        cmask[tid] = (tid < NL && ymask[j * NL + tid] != 0) ? 1.f : 0.f;
    __syncthreads();

    const float a_im   = fminf(fmaxf(d_im[0],   -1.f), 1.f);
    const float a_lang = fminf(fmaxf(d_lang[0], -1.f), 1.f);

    for (int t = tid; t < NM * NL; t += 256) {
        const int p = t >> 5, l = t & 31;
        sC[p * LP1 + l] = (cmask[l] != 0.f) ? NEGV : base[t];
    }
    if (tid < MP1) { sC[tid * LP1 + 32] = a_im; su[tid] = 0.f; }
    if (tid < NL)  sC[NM * LP1 + tid] = (cmask[tid] != 0.f) ? NEGV : a_lang;
    if (tid < LP1) sv[tid] = (cmask[tid] != 0.f) ? NEGV : 0.f;
    if (tid == 0) {
        float ns = 0.f;
        for (int l = 0; l < NL; ++l) ns += 1.f - cmask[l];
        const float nrm = -__logf(49.f + ns);
        meta[0] = ns;
        meta[1] = nrm;
        meta[2] = __logf(ns) + nrm;    // log_mu dustbin
        meta[3] = __logf(49.f) + nrm;  // log_nu dustbin
    }
    __syncthreads();
    const float nrm = meta[1];
    const int rid = tid >> 2, s = tid & 3;

    for (int it = 0; it < 10; ++it) {
        // ---- row update (u), LSE over 33 cols, 4 lanes per row ----
        if (rid < MP1) {
            const float ur = su[rid];
            float Mv[9];
            float mx = -3.0e38f;
            #pragma unroll
            for (int q = 0; q < 9; ++q) {
                const int l = s + 4 * q;
                const int lc = (l < LP1) ? l : (LP1 - 1);
                const float m_ = (sC[rid * LP1 + lc] + ur + sv[lc]) * INVREG;
                Mv[q] = (l < LP1) ? m_ : -3.0e38f;
                mx = fmaxf(mx, Mv[q]);
            }
            mx = fmaxf(mx, __shfl_xor(mx, 1, 64));
            mx = fmaxf(mx, __shfl_xor(mx, 2, 64));
            float sm = 0.f;
            #pragma unroll
            for (int q = 0; q < 9; ++q) sm += __expf(Mv[q] - mx);
            sm += __shfl_xor(sm, 1, 64);
            sm += __shfl_xor(sm, 2, 64);
            if (s == 0) {
                const float lse = __logf(sm) + mx;
                const float lmu = (rid < NM) ? nrm : meta[2];
                su[rid] = ur + REGV * (lmu - lse);
            }
        }
        __syncthreads();
        // ---- col update (v), LSE over 50 rows, skip masked cols ----
        if (rid < LP1 && cmask[rid] == 0.f) {
            const float vc = sv[rid];
            float Mv[13];
            float mx = -3.0e38f;
            #pragma unroll
            for (int q = 0; q < 13; ++q) {
                const int r = s + 4 * q;
                const int rc = (r < MP1) ? r : (MP1 - 1);
                const float m_ = (sC[rc * LP1 + rid] + su[rc] + vc) * INVREG;
                Mv[q] = (r < MP1) ? m_ : -3.0e38f;
                mx = fmaxf(mx, Mv[q]);
            }
            mx = fmaxf(mx, __shfl_xor(mx, 1, 64));
            mx = fmaxf(mx, __shfl_xor(mx, 2, 64));
            float sm = 0.f;
            #pragma unroll
            for (int q = 0; q < 13; ++q) sm += __expf(Mv[q] - mx);
            sm += __shfl_xor(sm, 1, 64);
            sm += __shfl_xor(sm, 2, 64);
            if (s == 0) {
                const float lse = __logf(sm) + mx;
                const float lnu = (rid < NL) ? nrm : meta[3];
                sv[rid] = vc + REGV * (lnu - lse);
            }
        }
        __syncthreads();
    }

    // ---- Zm output + OT score ----
    float ot = 0.f;
    for (int t = tid; t < MP1 * LP1; t += 256) {
        const int p = t / LP1;
        const int l = t - p * LP1;
        const float z = sC[t];
        const float zm = __expf((z + su[p] + sv[l]) * INVREG - nrm);
        base[t] = zm;
        if (p < NM && l < NL) ot = fmaf(z, zm, ot);
    }
    #pragma unroll
    for (int o = 32; o > 0; o >>= 1) ot += __shfl_xor(ot, o, 64);
    if ((tid & 63) == 0) wred[tid >> 6] = ot;
    __syncthreads();
    if (tid == 0) scores2[b] = (wred[0] + wred[1] + wred[2] + wred[3]) * 10.0f; // /TEMP
}

// ---------------------------------------------------------------- InfoNCE loss
__global__ __launch_bounds__(256) void loss_kernel(
    const float* __restrict__ s2, float* __restrict__ out)
{
    const int i = threadIdx.x;
    const int g = i >> 2;
    const float pos = s2[i * 64 + g];
    float mx = -3.0e38f;
    for (int jj = 0; jj < 64; ++jj) mx = fmaxf(mx, s2[i * 64 + jj]);
    float sm = 0.f;
    for (int jj = 0; jj < 64; ++jj) sm += __expf(s2[i * 64 + jj] - mx);
    const float lse1 = __logf(sm) + mx;

    float mx2 = -3.0e38f;
    for (int k = 0; k < 256; ++k) {
        const bool allowed = ((k >> 2) != g) || (k == i);
        if (allowed) mx2 = fmaxf(mx2, s2[k * 64 + g]);
    }
    float sm2 = 0.f;
    for (int k = 0; k < 256; ++k) {
        const bool allowed = ((k >> 2) != g) || (k == i);
        if (allowed) sm2 += __expf(s2[k * 64 + g] - mx2);
    }
    const float lse2 = __logf(sm2) + mx2;

    float li = 0.5f * (lse1 - pos) + 0.5f * (lse2 - pos);
    #pragma unroll
    for (int o = 32; o > 0; o >>= 1) li += __shfl_xor(li, o, 64);
    __shared__ float wred[4];
    if ((i & 63) == 0) wred[i >> 6] = li;
    __syncthreads();
    if (i == 0) out[0] = (wred[0] + wred[1] + wred[2] + wred[3]) * (1.0f / 256.0f);
}

// ---------------------------------------------------------------- launch
extern "C" void kernel_launch(void* const* d_in, const int* in_sizes, int n_in,
                              void* d_out, int out_size, void* d_ws, size_t ws_size,
                              hipStream_t stream)
{
    const float* x      = (const float*)d_in[0];
    const float* y      = (const float*)d_in[1];
    const float* d_im   = (const float*)d_in[2];
    const float* d_lang = (const float*)d_in[3];
    const int* ymask    = (const int*)d_in[4];
    float* out = (float*)d_out;
    float* ws  = (float*)d_ws;

    float* invx = ws;              // 12544
    float* invy = ws + XROWS;      // 2048
    float* s2   = ws + XROWS + YROWS; // 16384

    norm_kernel<<<(XROWS + YROWS) / 4, 256, 0, stream>>>(x, y, invx, invy);
    gemm_kernel<<<(XROWS / 128) * (YROWS / 128), 256, 0, stream>>>(x, y, invx, invy, out);
    sinkhorn_kernel<<<16384, 256, 0, stream>>>(out, ymask, d_im, d_lang, s2);
    loss_kernel<<<1, 256, 0, stream>>>(s2, out + (size_t)16384 * BSTRIDE);
}

// Round 3
// 390.477 us; speedup vs baseline: 1.9375x; 1.9375x over previous
//
#include <hip/hip_runtime.h>
#include <math.h>

#define XROWS 12544      // 256*49
#define YROWS 2048       // 64*32
#define HD 512
#define NM 49
#define NL 32
#define MP1 50
#define LP1 33
#define BSTRIDE 1650     // (m+1)*(L+1)
#define NEGV -1000000.0f
#define REGV 0.1f
#define INVREG 10.0f

typedef __attribute__((ext_vector_type(8))) short short8;
typedef __attribute__((ext_vector_type(4))) float floatx4;

__device__ __forceinline__ unsigned short f2bf(float f) {
    unsigned int u = __builtin_bit_cast(unsigned int, f);
    u = (u + 0x7FFFu + ((u >> 16) & 1u)) >> 16;
    return (unsigned short)u;
}

__device__ __forceinline__ void gload_lds16(const void* g, void* l) {
    typedef const __attribute__((address_space(1))) unsigned int* gp_t;
    typedef __attribute__((address_space(3))) unsigned int* lp_t;
    __builtin_amdgcn_global_load_lds((gp_t)g, (lp_t)l, 16, 0, 0);
}

// ------------------------------------------------ normalize + cast to bf16
__global__ __launch_bounds__(256) void normcvt_kernel(
    const float* __restrict__ x, const float* __restrict__ y,
    unsigned short* __restrict__ xb, unsigned short* __restrict__ yb)
{
    const int wid = blockIdx.x * 4 + (threadIdx.x >> 6);
    const int lane = threadIdx.x & 63;
    if (wid >= XROWS + YROWS) return;
    const float* src;
    unsigned short* dst;
    if (wid < XROWS) { src = x + (size_t)wid * HD;           dst = xb + (size_t)wid * HD; }
    else             { src = y + (size_t)(wid - XROWS) * HD; dst = yb + (size_t)(wid - XROWS) * HD; }
    const float4 v0 = *(const float4*)(src + lane * 8);
    const float4 v1 = *(const float4*)(src + lane * 8 + 4);
    float s = v0.x*v0.x + v0.y*v0.y + v0.z*v0.z + v0.w*v0.w
            + v1.x*v1.x + v1.y*v1.y + v1.z*v1.z + v1.w*v1.w;
    #pragma unroll
    for (int o = 32; o > 0; o >>= 1) s += __shfl_xor(s, o, 64);
    const float inv = 1.0f / fmaxf(sqrtf(s), 1e-12f);
    short8 ov;
    ov[0] = (short)f2bf(v0.x * inv); ov[1] = (short)f2bf(v0.y * inv);
    ov[2] = (short)f2bf(v0.z * inv); ov[3] = (short)f2bf(v0.w * inv);
    ov[4] = (short)f2bf(v1.x * inv); ov[5] = (short)f2bf(v1.y * inv);
    ov[6] = (short)f2bf(v1.z * inv); ov[7] = (short)f2bf(v1.w * inv);
    *(short8*)(dst + lane * 8) = ov;
}

// ------------------------------------------------ bf16 MFMA GEMM
// C[12544 x 2048] = Xb * Yb^T, scattered into d_out at ((i*64+j)*1650 + p*32+l)
#define BM 128
#define BN 128
#define BK 32

__global__ __launch_bounds__(256) void mfma_gemm_kernel(
    const unsigned short* __restrict__ xb, const unsigned short* __restrict__ yb,
    float* __restrict__ outS)
{
    __shared__ unsigned short lA[BM * BK];   // 8 KB, row-major [128][32]
    __shared__ unsigned short lB[BN * BK];   // 8 KB, row-major [128][32]
    const int tid  = threadIdx.x;
    const int lane = tid & 63;
    const int wv   = tid >> 6;          // wave 0..3
    const int wr   = wv >> 1, wc = wv & 1;
    const int mblk = blockIdx.x >> 4;   // 0..97
    const int nblk = blockIdx.x & 15;   // fastest -> A-tile L2 reuse
    const int m0 = mblk * BM, n0 = nblk * BN;

    floatx4 acc[4][4] = {};

    const int srow = tid >> 2;          // 0..63 (staging row within pass)
    const int skq  = (tid & 3) * 8;     // k offset, 8 bf16 = 16 B

    for (int kt = 0; kt < HD / BK; ++kt) {
        const int k0 = kt * BK;
        __syncthreads();                 // previous compute done before overwrite
        // stage A (2 passes of 64 rows) and B — linear LDS, wave-uniform base
        gload_lds16(xb + (size_t)(m0 +      srow) * HD + k0 + skq, (char*)lA +        wv * 1024);
        gload_lds16(xb + (size_t)(m0 + 64 + srow) * HD + k0 + skq, (char*)lA + 4096 + wv * 1024);
        gload_lds16(yb + (size_t)(n0 +      srow) * HD + k0 + skq, (char*)lB +        wv * 1024);
        gload_lds16(yb + (size_t)(n0 + 64 + srow) * HD + k0 + skq, (char*)lB + 4096 + wv * 1024);
        __syncthreads();                 // compiler drains vmcnt(0) here

        const int krow = (lane >> 4) * 8;
        short8 aF[4], bF[4];
        #pragma unroll
        for (int mi = 0; mi < 4; ++mi)
            aF[mi] = *(const short8*)&lA[(wr * 64 + mi * 16 + (lane & 15)) * BK + krow];
        #pragma unroll
        for (int ni = 0; ni < 4; ++ni)
            bF[ni] = *(const short8*)&lB[(wc * 64 + ni * 16 + (lane & 15)) * BK + krow];
        #pragma unroll
        for (int mi = 0; mi < 4; ++mi)
            #pragma unroll
            for (int ni = 0; ni < 4; ++ni)
                acc[mi][ni] = __builtin_amdgcn_mfma_f32_16x16x32_bf16(
                    aF[mi], bF[ni], acc[mi][ni], 0, 0, 0);
    }

    // epilogue: C/D layout col=lane&15, row=(lane>>4)*4+q  (m89-verified)
    #pragma unroll
    for (int mi = 0; mi < 4; ++mi) {
        #pragma unroll
        for (int q = 0; q < 4; ++q) {
            const int r = m0 + wr * 64 + mi * 16 + (lane >> 4) * 4 + q;
            const int i = r / NM;
            const int p = r - i * NM;
            #pragma unroll
            for (int ni = 0; ni < 4; ++ni) {
                const int c = n0 + wc * 64 + ni * 16 + (lane & 15);
                const int j = c >> 5, lc = c & 31;
                outS[(size_t)(i * 64 + j) * BSTRIDE + p * 32 + lc] = acc[mi][ni][q];
            }
        }
    }
}

// ---------------------------------------------------------------- sinkhorn per pair
__global__ __launch_bounds__(256) void sinkhorn_kernel(
    float* __restrict__ outZ,
    const int* __restrict__ ymask,
    const float* __restrict__ d_im, const float* __restrict__ d_lang,
    float* __restrict__ scores2)
{
    const int b = blockIdx.x;
    const int j = b & 63;
    const int tid = threadIdx.x;
    __shared__ float sC[MP1 * LP1];
    __shared__ float su[MP1];
    __shared__ float sv[LP1];
    __shared__ float cmask[LP1];
    __shared__ float meta[4];
    __shared__ float wred[4];
    float* base = outZ + (size_t)b * BSTRIDE;

    if (tid < LP1)
        cmask[tid] = (tid < NL && ymask[j * NL + tid] != 0) ? 1.f : 0.f;
    __syncthreads();

    const float a_im   = fminf(fmaxf(d_im[0],   -1.f), 1.f);
    const float a_lang = fminf(fmaxf(d_lang[0], -1.f), 1.f);

    for (int t = tid; t < NM * NL; t += 256) {
        const int p = t >> 5, l = t & 31;
        sC[p * LP1 + l] = (cmask[l] != 0.f) ? NEGV : base[t];
    }
    if (tid < MP1) { sC[tid * LP1 + 32] = a_im; su[tid] = 0.f; }
    if (tid < NL)  sC[NM * LP1 + tid] = (cmask[tid] != 0.f) ? NEGV : a_lang;
    if (tid < LP1) sv[tid] = (cmask[tid] != 0.f) ? NEGV : 0.f;
    if (tid == 0) {
        float ns = 0.f;
        for (int l = 0; l < NL; ++l) ns += 1.f - cmask[l];
        const float nrm = -__logf(49.f + ns);
        meta[0] = ns;
        meta[1] = nrm;
        meta[2] = __logf(ns) + nrm;    // log_mu dustbin
        meta[3] = __logf(49.f) + nrm;  // log_nu dustbin
    }
    __syncthreads();
    const float nrm = meta[1];
    const int rid = tid >> 2, s = tid & 3;

    for (int it = 0; it < 10; ++it) {
        // ---- row update (u), LSE over 33 cols, 4 lanes per row ----
        if (rid < MP1) {
            const float ur = su[rid];
            float Mv[9];
            float mx = -3.0e38f;
            #pragma unroll
            for (int q = 0; q < 9; ++q) {
                const int l = s + 4 * q;
                const int lc = (l < LP1) ? l : (LP1 - 1);
                const float m_ = (sC[rid * LP1 + lc] + ur + sv[lc]) * INVREG;
                Mv[q] = (l < LP1) ? m_ : -3.0e38f;
                mx = fmaxf(mx, Mv[q]);
            }
            mx = fmaxf(mx, __shfl_xor(mx, 1, 64));
            mx = fmaxf(mx, __shfl_xor(mx, 2, 64));
            float sm = 0.f;
            #pragma unroll
            for (int q = 0; q < 9; ++q) sm += __expf(Mv[q] - mx);
            sm += __shfl_xor(sm, 1, 64);
            sm += __shfl_xor(sm, 2, 64);
            if (s == 0) {
                const float lse = __logf(sm) + mx;
                const float lmu = (rid < NM) ? nrm : meta[2];
                su[rid] = ur + REGV * (lmu - lse);
            }
        }
        __syncthreads();
        // ---- col update (v), LSE over 50 rows, skip masked cols ----
        if (rid < LP1 && cmask[rid] == 0.f) {
            const float vc = sv[rid];
            float Mv[13];
            float mx = -3.0e38f;
            #pragma unroll
            for (int q = 0; q < 13; ++q) {
                const int r = s + 4 * q;
                const int rc = (r < MP1) ? r : (MP1 - 1);
                const float m_ = (sC[rc * LP1 + rid] + su[rc] + vc) * INVREG;
                Mv[q] = (r < MP1) ? m_ : -3.0e38f;
                mx = fmaxf(mx, Mv[q]);
            }
            mx = fmaxf(mx, __shfl_xor(mx, 1, 64));
            mx = fmaxf(mx, __shfl_xor(mx, 2, 64));
            float sm = 0.f;
            #pragma unroll
            for (int q = 0; q < 13; ++q) sm += __expf(Mv[q] - mx);
            sm += __shfl_xor(sm, 1, 64);
            sm += __shfl_xor(sm, 2, 64);
            if (s == 0) {
                const float lse = __logf(sm) + mx;
                const float lnu = (rid < NL) ? nrm : meta[3];
                sv[rid] = vc + REGV * (lnu - lse);
            }
        }
        __syncthreads();
    }

    // ---- Zm output + OT score ----
    float ot = 0.f;
    for (int t = tid; t < MP1 * LP1; t += 256) {
        const int p = t / LP1;
        const int l = t - p * LP1;
        const float z = sC[t];
        const float zm = __expf((z + su[p] + sv[l]) * INVREG - nrm);
        base[t] = zm;
        if (p < NM && l < NL) ot = fmaf(z, zm, ot);
    }
    #pragma unroll
    for (int o = 32; o > 0; o >>= 1) ot += __shfl_xor(ot, o, 64);
    if ((tid & 63) == 0) wred[tid >> 6] = ot;
    __syncthreads();
    if (tid == 0) scores2[b] = (wred[0] + wred[1] + wred[2] + wred[3]) * 10.0f; // /TEMP
}

// ---------------------------------------------------------------- InfoNCE loss
__global__ __launch_bounds__(256) void loss_kernel(
    const float* __restrict__ s2, float* __restrict__ out)
{
    const int i = threadIdx.x;
    const int g = i >> 2;
    const float pos = s2[i * 64 + g];
    float mx = -3.0e38f;
    for (int jj = 0; jj < 64; ++jj) mx = fmaxf(mx, s2[i * 64 + jj]);
    float sm = 0.f;
    for (int jj = 0; jj < 64; ++jj) sm += __expf(s2[i * 64 + jj] - mx);
    const float lse1 = __logf(sm) + mx;

    float mx2 = -3.0e38f;
    for (int k = 0; k < 256; ++k) {
        const bool allowed = ((k >> 2) != g) || (k == i);
        if (allowed) mx2 = fmaxf(mx2, s2[k * 64 + g]);
    }
    float sm2 = 0.f;
    for (int k = 0; k < 256; ++k) {
        const bool allowed = ((k >> 2) != g) || (k == i);
        if (allowed) sm2 += __expf(s2[k * 64 + g] - mx2);
    }
    const float lse2 = __logf(sm2) + mx2;

    float li = 0.5f * (lse1 - pos) + 0.5f * (lse2 - pos);
    #pragma unroll
    for (int o = 32; o > 0; o >>= 1) li += __shfl_xor(li, o, 64);
    __shared__ float wred[4];
    if ((i & 63) == 0) wred[i >> 6] = li;
    __syncthreads();
    if (i == 0) out[0] = (wred[0] + wred[1] + wred[2] + wred[3]) * (1.0f / 256.0f);
}

// ---------------------------------------------------------------- launch
extern "C" void kernel_launch(void* const* d_in, const int* in_sizes, int n_in,
                              void* d_out, int out_size, void* d_ws, size_t ws_size,
                              hipStream_t stream)
{
    const float* x      = (const float*)d_in[0];
    const float* y      = (const float*)d_in[1];
    const float* d_im   = (const float*)d_in[2];
    const float* d_lang = (const float*)d_in[3];
    const int* ymask    = (const int*)d_in[4];
    float* out = (float*)d_out;
    float* ws  = (float*)d_ws;

    float* s2          = ws;                                  // 16384 floats
    unsigned short* xb = (unsigned short*)(ws + 16384);       // 12544*512 bf16
    unsigned short* yb = xb + (size_t)XROWS * HD;             // 2048*512 bf16

    normcvt_kernel<<<(XROWS + YROWS + 3) / 4, 256, 0, stream>>>(x, y, xb, yb);
    mfma_gemm_kernel<<<(XROWS / BM) * (YROWS / BN), 256, 0, stream>>>(xb, yb, out);
    sinkhorn_kernel<<<16384, 256, 0, stream>>>(out, ymask, d_im, d_lang, s2);
    loss_kernel<<<1, 256, 0, stream>>>(s2, out + (size_t)16384 * BSTRIDE);
}

// Round 4
// 287.648 us; speedup vs baseline: 2.6301x; 1.3575x over previous
//
#include <hip/hip_runtime.h>
#include <math.h>

#define XROWS 12544      // 256*49
#define YROWS 2048       // 64*32
#define HD 512
#define NM 49
#define NL 32
#define MP1 50
#define LP1 33
#define BSTRIDE 1650     // (m+1)*(L+1)
#define REGV 0.1f
#define INVREG 10.0f

typedef __attribute__((ext_vector_type(8))) short short8;
typedef __attribute__((ext_vector_type(4))) float floatx4;

__device__ __forceinline__ unsigned short f2bf(float f) {
    unsigned int u = __builtin_bit_cast(unsigned int, f);
    u = (u + 0x7FFFu + ((u >> 16) & 1u)) >> 16;
    return (unsigned short)u;
}

__device__ __forceinline__ void gload_lds16(const void* g, void* l) {
    typedef const __attribute__((address_space(1))) unsigned int* gp_t;
    typedef __attribute__((address_space(3))) unsigned int* lp_t;
    __builtin_amdgcn_global_load_lds((gp_t)g, (lp_t)l, 16, 0, 0);
}

// ------------------------------------------------ normalize + cast to bf16
__global__ __launch_bounds__(256) void normcvt_kernel(
    const float* __restrict__ x, const float* __restrict__ y,
    unsigned short* __restrict__ xb, unsigned short* __restrict__ yb)
{
    const int wid = blockIdx.x * 4 + (threadIdx.x >> 6);
    const int lane = threadIdx.x & 63;
    if (wid >= XROWS + YROWS) return;
    const float* src;
    unsigned short* dst;
    if (wid < XROWS) { src = x + (size_t)wid * HD;           dst = xb + (size_t)wid * HD; }
    else             { src = y + (size_t)(wid - XROWS) * HD; dst = yb + (size_t)(wid - XROWS) * HD; }
    const float4 v0 = *(const float4*)(src + lane * 8);
    const float4 v1 = *(const float4*)(src + lane * 8 + 4);
    float s = v0.x*v0.x + v0.y*v0.y + v0.z*v0.z + v0.w*v0.w
            + v1.x*v1.x + v1.y*v1.y + v1.z*v1.z + v1.w*v1.w;
    #pragma unroll
    for (int o = 32; o > 0; o >>= 1) s += __shfl_xor(s, o, 64);
    const float inv = 1.0f / fmaxf(sqrtf(s), 1e-12f);
    short8 ov;
    ov[0] = (short)f2bf(v0.x * inv); ov[1] = (short)f2bf(v0.y * inv);
    ov[2] = (short)f2bf(v0.z * inv); ov[3] = (short)f2bf(v0.w * inv);
    ov[4] = (short)f2bf(v1.x * inv); ov[5] = (short)f2bf(v1.y * inv);
    ov[6] = (short)f2bf(v1.z * inv); ov[7] = (short)f2bf(v1.w * inv);
    *(short8*)(dst + lane * 8) = ov;
}

// ------------------------------------------------ bf16 MFMA GEMM
// C[12544 x 2048] = Xb * Yb^T, scattered into d_out at ((i*64+j)*1650 + p*32+l)
#define BM 128
#define BN 128
#define BK 32

__global__ __launch_bounds__(256) void mfma_gemm_kernel(
    const unsigned short* __restrict__ xb, const unsigned short* __restrict__ yb,
    float* __restrict__ outS)
{
    __shared__ unsigned short lA[BM * BK];   // 8 KB, row-major [128][32]
    __shared__ unsigned short lB[BN * BK];   // 8 KB, row-major [128][32]
    const int tid  = threadIdx.x;
    const int lane = tid & 63;
    const int wv   = tid >> 6;          // wave 0..3
    const int wr   = wv >> 1, wc = wv & 1;
    const int mblk = blockIdx.x >> 4;   // 0..97
    const int nblk = blockIdx.x & 15;   // fastest -> A-tile L2 reuse
    const int m0 = mblk * BM, n0 = nblk * BN;

    floatx4 acc[4][4] = {};

    const int srow = tid >> 2;          // 0..63 (staging row within pass)
    const int skq  = (tid & 3) * 8;     // k offset, 8 bf16 = 16 B

    for (int kt = 0; kt < HD / BK; ++kt) {
        const int k0 = kt * BK;
        __syncthreads();                 // previous compute done before overwrite
        gload_lds16(xb + (size_t)(m0 +      srow) * HD + k0 + skq, (char*)lA +        wv * 1024);
        gload_lds16(xb + (size_t)(m0 + 64 + srow) * HD + k0 + skq, (char*)lA + 4096 + wv * 1024);
        gload_lds16(yb + (size_t)(n0 +      srow) * HD + k0 + skq, (char*)lB +        wv * 1024);
        gload_lds16(yb + (size_t)(n0 + 64 + srow) * HD + k0 + skq, (char*)lB + 4096 + wv * 1024);
        __syncthreads();                 // compiler drains vmcnt(0) here

        const int krow = (lane >> 4) * 8;
        short8 aF[4], bF[4];
        #pragma unroll
        for (int mi = 0; mi < 4; ++mi)
            aF[mi] = *(const short8*)&lA[(wr * 64 + mi * 16 + (lane & 15)) * BK + krow];
        #pragma unroll
        for (int ni = 0; ni < 4; ++ni)
            bF[ni] = *(const short8*)&lB[(wc * 64 + ni * 16 + (lane & 15)) * BK + krow];
        #pragma unroll
        for (int mi = 0; mi < 4; ++mi)
            #pragma unroll
            for (int ni = 0; ni < 4; ++ni)
                acc[mi][ni] = __builtin_amdgcn_mfma_f32_16x16x32_bf16(
                    aF[mi], bF[ni], acc[mi][ni], 0, 0, 0);
    }

    // epilogue: C/D layout col=lane&15, row=(lane>>4)*4+q  (m89-verified)
    #pragma unroll
    for (int mi = 0; mi < 4; ++mi) {
        #pragma unroll
        for (int q = 0; q < 4; ++q) {
            const int r = m0 + wr * 64 + mi * 16 + (lane >> 4) * 4 + q;
            const int i = r / NM;
            const int p = r - i * NM;
            #pragma unroll
            for (int ni = 0; ni < 4; ++ni) {
                const int c = n0 + wc * 64 + ni * 16 + (lane & 15);
                const int j = c >> 5, lc = c & 31;
                outS[(size_t)(i * 64 + j) * BSTRIDE + p * 32 + lc] = acc[mi][ni][q];
            }
        }
    }
}

// ---------------------------------------------------------------- sinkhorn (multiplicative)
// eu[p] = mu'[p] / sum_l K[p,l] ev[l];  ev[l] = nu'[l] / sum_p K[p,l] eu[p]
// with K = exp(C/reg), mu' = {1,..,1, ns}, nu' = {1|0,.., 49}, Zm = K*eu*ev.
__global__ __launch_bounds__(256) void sinkhorn_kernel(
    float* __restrict__ outZ,
    const int* __restrict__ ymask,
    const float* __restrict__ d_im, const float* __restrict__ d_lang,
    float* __restrict__ scores2)
{
    const int b = blockIdx.x;
    const int j = b & 63;
    const int tid = threadIdx.x;
    __shared__ float sKr[MP1 * 36];   // row-major K, cols 33..35 = 0
    __shared__ float sKc[LP1 * 52];   // transposed K, rows 50,51 = 0
    __shared__ float sS[NM * NL];     // raw scores for ot
    __shared__ float seu[52];         // eu, [50..51] = 0
    __shared__ float sev[36];         // ev, [33..35] = 0
    __shared__ float cmask[LP1];
    __shared__ float meta[1];
    __shared__ float wred[4];
    float* base = outZ + (size_t)b * BSTRIDE;

    if (tid < LP1)
        cmask[tid] = (tid < NL && ymask[j * NL + tid] != 0) ? 1.f : 0.f;
    if (tid >= 40 && tid < 92) seu[tid - 40] = 0.f;   // zero all (pads stay 0)
    if (tid >= 96 && tid < 99) sev[33 + tid - 96] = 0.f;
    __syncthreads();

    const float kim   = __expf(fminf(fmaxf(d_im[0],   -1.f), 1.f) * INVREG);
    const float klang = __expf(fminf(fmaxf(d_lang[0], -1.f), 1.f) * INVREG);

    // scores block -> K (both layouts) + raw copy
    for (int t = tid; t < NM * NL; t += 256) {
        const int p = t >> 5, l = t & 31;
        const float sc = base[t];
        sS[t] = sc;
        const float k = (cmask[l] != 0.f) ? 0.f : __expf(sc * INVREG);
        sKr[p * 36 + l] = k;
        sKc[l * 52 + p] = k;
    }
    if (tid < MP1) {                       // dustbin col l=32 + row pads
        sKr[tid * 36 + 32] = kim;
        sKc[32 * 52 + tid] = kim;
        sKr[tid * 36 + 33] = 0.f;
        sKr[tid * 36 + 34] = 0.f;
        sKr[tid * 36 + 35] = 0.f;
    }
    if (tid >= 128 && tid < 128 + NL) {    // dustbin row p=49
        const int l = tid - 128;
        const float k = (cmask[l] != 0.f) ? 0.f : klang;
        sKr[NM * 36 + l] = k;
        sKc[l * 52 + NM] = k;
    }
    if (tid >= 192 && tid < 192 + LP1) {   // sKc row pads + ev init
        const int l = tid - 192;
        sKc[l * 52 + 50] = 0.f;
        sKc[l * 52 + 51] = 0.f;
        sev[l] = (l < NL && cmask[l] != 0.f) ? 0.f : 1.f;
    }
    if (tid == 0) {
        float ns = 0.f;
        for (int l = 0; l < NL; ++l) ns += 1.f - cmask[l];
        meta[0] = ns;
    }
    __syncthreads();
    const float ns = meta[0];
    const int rid = tid >> 2, s = tid & 3;
    const float mup = (rid < NM) ? 1.f : ns;    // used when rid < 50
    const float nup = (rid < NL) ? 1.f : 49.f;  // used when rid < 33
    const bool colv = (rid < LP1) && (cmask[rid < LP1 ? rid : 0] == 0.f);

    for (int it = 0; it < 10; ++it) {
        // ---- u update: S_p = sum_l K[p,l] ev[l], 4 lanes per row ----
        if (rid < MP1) {
            float S = 0.f;
            #pragma unroll
            for (int q = 0; q < 9; ++q) {
                const int l = s + 4 * q;
                S = fmaf(sKr[rid * 36 + l], sev[l], S);
            }
            S += __shfl_xor(S, 1, 64);
            S += __shfl_xor(S, 2, 64);
            if (s == 0) seu[rid] = __fdividef(mup, S);
        }
        __syncthreads();
        // ---- v update: S_l = sum_p K[p,l] eu[p], 4 lanes per col ----
        if (colv) {
            float S = 0.f;
            #pragma unroll
            for (int q = 0; q < 13; ++q) {
                const int r = s + 4 * q;
                S = fmaf(sKc[rid * 52 + r], seu[r], S);
            }
            S += __shfl_xor(S, 1, 64);
            S += __shfl_xor(S, 2, 64);
            if (s == 0) sev[rid] = __fdividef(nup, S);
        }
        __syncthreads();
    }

    // ---- Zm output + OT score ----
    float ot = 0.f;
    for (int t = tid; t < MP1 * LP1; t += 256) {
        const int p = t / LP1;
        const int l = t - p * LP1;
        const float zm = sKr[p * 36 + l] * seu[p] * sev[l];
        base[t] = zm;
        if (p < NM && l < NL) ot = fmaf(sS[p * NL + l], zm, ot);
    }
    #pragma unroll
    for (int o = 32; o > 0; o >>= 1) ot += __shfl_xor(ot, o, 64);
    if ((tid & 63) == 0) wred[tid >> 6] = ot;
    __syncthreads();
    if (tid == 0) scores2[b] = (wred[0] + wred[1] + wred[2] + wred[3]) * 10.0f; // /TEMP
}

// ---------------------------------------------------------------- InfoNCE loss
__global__ __launch_bounds__(256) void loss_kernel(
    const float* __restrict__ s2, float* __restrict__ out)
{
    const int i = threadIdx.x;
    const int g = i >> 2;
    const float pos = s2[i * 64 + g];
    float mx = -3.0e38f;
    for (int jj = 0; jj < 64; ++jj) mx = fmaxf(mx, s2[i * 64 + jj]);
    float sm = 0.f;
    for (int jj = 0; jj < 64; ++jj) sm += __expf(s2[i * 64 + jj] - mx);
    const float lse1 = __logf(sm) + mx;

    float mx2 = -3.0e38f;
    for (int k = 0; k < 256; ++k) {
        const bool allowed = ((k >> 2) != g) || (k == i);
        if (allowed) mx2 = fmaxf(mx2, s2[k * 64 + g]);
    }
    float sm2 = 0.f;
    for (int k = 0; k < 256; ++k) {
        const bool allowed = ((k >> 2) != g) || (k == i);
        if (allowed) sm2 += __expf(s2[k * 64 + g] - mx2);
    }
    const float lse2 = __logf(sm2) + mx2;

    float li = 0.5f * (lse1 - pos) + 0.5f * (lse2 - pos);
    #pragma unroll
    for (int o = 32; o > 0; o >>= 1) li += __shfl_xor(li, o, 64);
    __shared__ float wred[4];
    if ((i & 63) == 0) wred[i >> 6] = li;
    __syncthreads();
    if (i == 0) out[0] = (wred[0] + wred[1] + wred[2] + wred[3]) * (1.0f / 256.0f);
}

// ---------------------------------------------------------------- launch
extern "C" void kernel_launch(void* const* d_in, const int* in_sizes, int n_in,
                              void* d_out, int out_size, void* d_ws, size_t ws_size,
                              hipStream_t stream)
{
    const float* x      = (const float*)d_in[0];
    const float* y      = (const float*)d_in[1];
    const float* d_im   = (const float*)d_in[2];
    const float* d_lang = (const float*)d_in[3];
    const int* ymask    = (const int*)d_in[4];
    float* out = (float*)d_out;
    float* ws  = (float*)d_ws;

    float* s2          = ws;                                  // 16384 floats
    unsigned short* xb = (unsigned short*)(ws + 16384);       // 12544*512 bf16
    unsigned short* yb = xb + (size_t)XROWS * HD;             // 2048*512 bf16

    normcvt_kernel<<<(XROWS + YROWS + 3) / 4, 256, 0, stream>>>(x, y, xb, yb);
    mfma_gemm_kernel<<<(XROWS / BM) * (YROWS / BN), 256, 0, stream>>>(xb, yb, out);
    sinkhorn_kernel<<<16384, 256, 0, stream>>>(out, ymask, d_im, d_lang, s2);
    loss_kernel<<<1, 256, 0, stream>>>(s2, out + (size_t)16384 * BSTRIDE);
}

// Round 5
// 271.094 us; speedup vs baseline: 2.7907x; 1.0611x over previous
//
#include <hip/hip_runtime.h>
#include <math.h>

#define XROWS 12544      // 256*49
#define YROWS 2048       // 64*32
#define HD 512
#define NM 49
#define NL 32
#define MP1 50
#define LP1 33
#define BSTRIDE 1650     // (m+1)*(L+1)
#define INVREG 10.0f

typedef __attribute__((ext_vector_type(8))) short short8;
typedef __attribute__((ext_vector_type(4))) float floatx4;

__device__ __forceinline__ unsigned short f2bf(float f) {
    unsigned int u = __builtin_bit_cast(unsigned int, f);
    u = (u + 0x7FFFu + ((u >> 16) & 1u)) >> 16;
    return (unsigned short)u;
}

__device__ __forceinline__ void gload_lds16(const void* g, void* l) {
    typedef const __attribute__((address_space(1))) unsigned int* gp_t;
    typedef __attribute__((address_space(3))) unsigned int* lp_t;
    __builtin_amdgcn_global_load_lds((gp_t)g, (lp_t)l, 16, 0, 0);
}

// ------------------------------------------------ normalize + cast to bf16
__global__ __launch_bounds__(256) void normcvt_kernel(
    const float* __restrict__ x, const float* __restrict__ y,
    unsigned short* __restrict__ xb, unsigned short* __restrict__ yb)
{
    const int wid = blockIdx.x * 4 + (threadIdx.x >> 6);
    const int lane = threadIdx.x & 63;
    if (wid >= XROWS + YROWS) return;
    const float* src;
    unsigned short* dst;
    if (wid < XROWS) { src = x + (size_t)wid * HD;           dst = xb + (size_t)wid * HD; }
    else             { src = y + (size_t)(wid - XROWS) * HD; dst = yb + (size_t)(wid - XROWS) * HD; }
    const float4 v0 = *(const float4*)(src + lane * 8);
    const float4 v1 = *(const float4*)(src + lane * 8 + 4);
    float s = v0.x*v0.x + v0.y*v0.y + v0.z*v0.z + v0.w*v0.w
            + v1.x*v1.x + v1.y*v1.y + v1.z*v1.z + v1.w*v1.w;
    #pragma unroll
    for (int o = 32; o > 0; o >>= 1) s += __shfl_xor(s, o, 64);
    const float inv = 1.0f / fmaxf(sqrtf(s), 1e-12f);
    short8 ov;
    ov[0] = (short)f2bf(v0.x * inv); ov[1] = (short)f2bf(v0.y * inv);
    ov[2] = (short)f2bf(v0.z * inv); ov[3] = (short)f2bf(v0.w * inv);
    ov[4] = (short)f2bf(v1.x * inv); ov[5] = (short)f2bf(v1.y * inv);
    ov[6] = (short)f2bf(v1.z * inv); ov[7] = (short)f2bf(v1.w * inv);
    *(short8*)(dst + lane * 8) = ov;
}

// ------------------------------------------------ bf16 MFMA GEMM
// C[12544 x 2048] = Xb * Yb^T, scattered into d_out at ((i*64+j)*1650 + p*32+l)
#define BM 128
#define BN 128
#define BK 32

__global__ __launch_bounds__(256) void mfma_gemm_kernel(
    const unsigned short* __restrict__ xb, const unsigned short* __restrict__ yb,
    float* __restrict__ outS)
{
    __shared__ unsigned short lA[BM * BK];   // 8 KB, row-major [128][32]
    __shared__ unsigned short lB[BN * BK];   // 8 KB, row-major [128][32]
    const int tid  = threadIdx.x;
    const int lane = tid & 63;
    const int wv   = tid >> 6;          // wave 0..3
    const int wr   = wv >> 1, wc = wv & 1;
    const int mblk = blockIdx.x >> 4;   // 0..97
    const int nblk = blockIdx.x & 15;   // fastest -> A-tile L2 reuse
    const int m0 = mblk * BM, n0 = nblk * BN;

    floatx4 acc[4][4] = {};

    const int srow = tid >> 2;          // 0..63 (staging row within pass)
    const int skq  = (tid & 3) * 8;     // k offset, 8 bf16 = 16 B

    for (int kt = 0; kt < HD / BK; ++kt) {
        const int k0 = kt * BK;
        __syncthreads();                 // previous compute done before overwrite
        gload_lds16(xb + (size_t)(m0 +      srow) * HD + k0 + skq, (char*)lA +        wv * 1024);
        gload_lds16(xb + (size_t)(m0 + 64 + srow) * HD + k0 + skq, (char*)lA + 4096 + wv * 1024);
        gload_lds16(yb + (size_t)(n0 +      srow) * HD + k0 + skq, (char*)lB +        wv * 1024);
        gload_lds16(yb + (size_t)(n0 + 64 + srow) * HD + k0 + skq, (char*)lB + 4096 + wv * 1024);
        __syncthreads();                 // compiler drains vmcnt(0) here

        const int krow = (lane >> 4) * 8;
        short8 aF[4], bF[4];
        #pragma unroll
        for (int mi = 0; mi < 4; ++mi)
            aF[mi] = *(const short8*)&lA[(wr * 64 + mi * 16 + (lane & 15)) * BK + krow];
        #pragma unroll
        for (int ni = 0; ni < 4; ++ni)
            bF[ni] = *(const short8*)&lB[(wc * 64 + ni * 16 + (lane & 15)) * BK + krow];
        #pragma unroll
        for (int mi = 0; mi < 4; ++mi)
            #pragma unroll
            for (int ni = 0; ni < 4; ++ni)
                acc[mi][ni] = __builtin_amdgcn_mfma_f32_16x16x32_bf16(
                    aF[mi], bF[ni], acc[mi][ni], 0, 0, 0);
    }

    // epilogue: C/D layout col=lane&15, row=(lane>>4)*4+q  (m89-verified)
    #pragma unroll
    for (int mi = 0; mi < 4; ++mi) {
        #pragma unroll
        for (int q = 0; q < 4; ++q) {
            const int r = m0 + wr * 64 + mi * 16 + (lane >> 4) * 4 + q;
            const int i = r / NM;
            const int p = r - i * NM;
            #pragma unroll
            for (int ni = 0; ni < 4; ++ni) {
                const int c = n0 + wc * 64 + ni * 16 + (lane & 15);
                const int j = c >> 5, lc = c & 31;
                outS[(size_t)(i * 64 + j) * BSTRIDE + p * 32 + lc] = acc[mi][ni][q];
            }
        }
    }
}

// ---------------------------------------------------------------- sinkhorn: one wave per pair
// Multiplicative form: eu[p] = mu'[p]/sum_l K[p,l] ev[l]; ev[l] = nu'[l]/sum_p K[p,l] eu[p]
// K row p lives in lane p's registers (33 VGPRs); column copy in LDS (stride 51, conflict-free).
__global__ __launch_bounds__(64) void sinkhorn_kernel(
    float* __restrict__ outZ,
    const int* __restrict__ ymask,
    const float* __restrict__ d_im, const float* __restrict__ d_lang,
    float* __restrict__ scores2)
{
    const int b = blockIdx.x;
    const int j = b & 63;
    const int lane = threadIdx.x;          // 0..63
    __shared__ alignas(16) float sKc[LP1 * 51 + 3];  // col-major K; reused as Zm staging
    __shared__ alignas(16) float seu[MP1];
    __shared__ alignas(16) float sev[36];
    __shared__ float cmask[NL];
    float* base = outZ + (size_t)b * BSTRIDE;

    // column masks + ns (valid token count) via ballot
    int mval = 0;
    if (lane < NL) { mval = (ymask[j * NL + lane] != 0); cmask[lane] = mval ? 1.f : 0.f; }
    const unsigned long long vb = __ballot(lane < NL && !mval);
    const float ns = (float)__popcll(vb);
    const float kim   = __expf(fminf(fmaxf(d_im[0],   -1.f), 1.f) * INVREG);
    const float klang = __expf(fminf(fmaxf(d_lang[0], -1.f), 1.f) * INVREG);
    if (lane < LP1) sev[lane] = (lane < NL && ((vb >> lane) & 1ull) == 0ull) ? 0.f : 1.f;
    __syncthreads();

    // build K row in registers (lane p owns row p); scores are L2/L3-hot from gemm
    float kr[33];
    if (lane < MP1) {
        if (lane < NM) {
            #pragma unroll
            for (int c = 0; c < NL; ++c) {
                const float sc = base[lane * NL + c];
                kr[c] = (cmask[c] != 0.f) ? 0.f : __expf(sc * INVREG);
            }
        } else {  // dustbin row p=49
            #pragma unroll
            for (int c = 0; c < NL; ++c)
                kr[c] = (cmask[c] != 0.f) ? 0.f : klang;
        }
        kr[32] = kim;   // dustbin col (and alpha corner for p=49)
        // column-major copy: sKc[c*51 + p] — banks (51c+p)%32=(19c+p)%32, conflict-free
        #pragma unroll
        for (int c = 0; c < 33; ++c) sKc[c * 51 + lane] = kr[c];
    }
    const float mup = (lane < NM) ? 1.f : ns;     // lane 49 -> ns
    const float nup = (lane < NL) ? 1.f : 49.f;   // lane 32 -> m=49
    const bool colActive = (lane < LP1) && !(lane < NL && ((vb >> lane) & 1ull) == 0ull && true) 
                           ? (lane < LP1 && (lane >= NL || ((vb >> lane) & 1ull))) : false;
    __syncthreads();

    for (int it = 0; it < 10; ++it) {
        // ---- u update: lane p computes S_p = sum_c K[p,c] ev[c] ----
        if (lane < MP1) {
            float evr[33];
            const float4* s4 = (const float4*)sev;   // broadcast b128 reads
            #pragma unroll
            for (int q = 0; q < 8; ++q) {
                const float4 v = s4[q];
                evr[q*4+0] = v.x; evr[q*4+1] = v.y; evr[q*4+2] = v.z; evr[q*4+3] = v.w;
            }
            evr[32] = sev[32];
            float a0 = 0.f, a1 = 0.f, a2 = 0.f, a3 = 0.f;
            #pragma unroll
            for (int c = 0; c < 32; c += 4) {
                a0 = fmaf(kr[c+0], evr[c+0], a0);
                a1 = fmaf(kr[c+1], evr[c+1], a1);
                a2 = fmaf(kr[c+2], evr[c+2], a2);
                a3 = fmaf(kr[c+3], evr[c+3], a3);
            }
            const float S = ((a0 + a1) + (a2 + a3)) + kr[32] * evr[32];
            seu[lane] = __fdividef(mup, S);
        }
        __syncthreads();
        // ---- v update: lane l computes S_l = sum_p K[p,l] eu[p] ----
        if (colActive) {
            float eur[50];
            const float4* s4 = (const float4*)seu;   // broadcast b128 reads
            #pragma unroll
            for (int q = 0; q < 12; ++q) {
                const float4 v = s4[q];
                eur[q*4+0] = v.x; eur[q*4+1] = v.y; eur[q*4+2] = v.z; eur[q*4+3] = v.w;
            }
            eur[48] = seu[48]; eur[49] = seu[49];
            const int cb = lane * 51;
            float a0 = 0.f, a1 = 0.f, a2 = 0.f, a3 = 0.f;
            #pragma unroll
            for (int p = 0; p < 48; p += 4) {
                a0 = fmaf(sKc[cb + p + 0], eur[p + 0], a0);
                a1 = fmaf(sKc[cb + p + 1], eur[p + 1], a1);
                a2 = fmaf(sKc[cb + p + 2], eur[p + 2], a2);
                a3 = fmaf(sKc[cb + p + 3], eur[p + 3], a3);
            }
            const float S = ((a0 + a1) + (a2 + a3))
                          + sKc[cb + 48] * eur[48] + sKc[cb + 49] * eur[49];
            sev[lane] = __fdividef(nup, S);
        }
        __syncthreads();
    }

    // ---- epilogue: Zm = K*eu*ev; ot = sum lnK * Zm over valid 49x32 block ----
    float ot = 0.f;
    if (lane < MP1) {
        const float eu = seu[lane];
        float evr[33];
        const float4* s4 = (const float4*)sev;
        #pragma unroll
        for (int q = 0; q < 8; ++q) {
            const float4 v = s4[q];
            evr[q*4+0] = v.x; evr[q*4+1] = v.y; evr[q*4+2] = v.z; evr[q*4+3] = v.w;
        }
        evr[32] = sev[32];
        #pragma unroll
        for (int c = 0; c < 33; ++c) {
            const float zm = kr[c] * eu * evr[c];
            sKc[lane * 33 + c] = zm;    // reuse sKc as row-major Zm staging
            if (lane < NM && c < NL && kr[c] > 0.f)
                ot = fmaf(__logf(kr[c]), zm, ot);   // lnK*zm = (10*S)*zm -> already /TEMP
        }
    }
    #pragma unroll
    for (int o = 32; o > 0; o >>= 1) ot += __shfl_xor(ot, o, 64);
    if (lane == 0) scores2[b] = ot;
    __syncthreads();
    // coalesced writeback: 1650 floats = 825 float2 (base is 8B-aligned for all b)
    for (int t2 = lane; t2 < 825; t2 += 64)
        *(float2*)(base + t2 * 2) = *(const float2*)&sKc[t2 * 2];
}

// ---------------------------------------------------------------- InfoNCE loss
__global__ __launch_bounds__(256) void loss_kernel(
    const float* __restrict__ s2, float* __restrict__ out)
{
    const int i = threadIdx.x;
    const int g = i >> 2;
    const float pos = s2[i * 64 + g];
    float mx = -3.0e38f;
    for (int jj = 0; jj < 64; ++jj) mx = fmaxf(mx, s2[i * 64 + jj]);
    float sm = 0.f;
    for (int jj = 0; jj < 64; ++jj) sm += __expf(s2[i * 64 + jj] - mx);
    const float lse1 = __logf(sm) + mx;

    float mx2 = -3.0e38f;
    for (int k = 0; k < 256; ++k) {
        const bool allowed = ((k >> 2) != g) || (k == i);
        if (allowed) mx2 = fmaxf(mx2, s2[k * 64 + g]);
    }
    float sm2 = 0.f;
    for (int k = 0; k < 256; ++k) {
        const bool allowed = ((k >> 2) != g) || (k == i);
        if (allowed) sm2 += __expf(s2[k * 64 + g] - mx2);
    }
    const float lse2 = __logf(sm2) + mx2;

    float li = 0.5f * (lse1 - pos) + 0.5f * (lse2 - pos);
    #pragma unroll
    for (int o = 32; o > 0; o >>= 1) li += __shfl_xor(li, o, 64);
    __shared__ float wred[4];
    if ((i & 63) == 0) wred[i >> 6] = li;
    __syncthreads();
    if (i == 0) out[0] = (wred[0] + wred[1] + wred[2] + wred[3]) * (1.0f / 256.0f);
}

// ---------------------------------------------------------------- launch
extern "C" void kernel_launch(void* const* d_in, const int* in_sizes, int n_in,
                              void* d_out, int out_size, void* d_ws, size_t ws_size,
                              hipStream_t stream)
{
    const float* x      = (const float*)d_in[0];
    const float* y      = (const float*)d_in[1];
    const float* d_im   = (const float*)d_in[2];
    const float* d_lang = (const float*)d_in[3];
    const int* ymask    = (const int*)d_in[4];
    float* out = (float*)d_out;
    float* ws  = (float*)d_ws;

    float* s2          = ws;                                  // 16384 floats
    unsigned short* xb = (unsigned short*)(ws + 16384);       // 12544*512 bf16
    unsigned short* yb = xb + (size_t)XROWS * HD;             // 2048*512 bf16

    normcvt_kernel<<<(XROWS + YROWS + 3) / 4, 256, 0, stream>>>(x, y, xb, yb);
    mfma_gemm_kernel<<<(XROWS / BM) * (YROWS / BN), 256, 0, stream>>>(xb, yb, out);
    sinkhorn_kernel<<<16384, 64, 0, stream>>>(out, ymask, d_im, d_lang, s2);
    loss_kernel<<<1, 256, 0, stream>>>(s2, out + (size_t)16384 * BSTRIDE);
}

// Round 6
// 230.888 us; speedup vs baseline: 3.2766x; 1.1741x over previous
//
#include <hip/hip_runtime.h>
#include <math.h>

#define XROWS 12544      // 256*49
#define YROWS 2048       // 64*32
#define HD 512
#define NM 49
#define NL 32
#define MP1 50
#define LP1 33
#define BSTRIDE 1650     // (m+1)*(L+1)
#define INVREG 10.0f

typedef __attribute__((ext_vector_type(8))) short short8;
typedef __attribute__((ext_vector_type(4))) float floatx4;

__device__ __forceinline__ unsigned short f2bf(float f) {
    unsigned int u = __builtin_bit_cast(unsigned int, f);
    u = (u + 0x7FFFu + ((u >> 16) & 1u)) >> 16;
    return (unsigned short)u;
}

__device__ __forceinline__ void gload_lds16(const void* g, void* l) {
    typedef const __attribute__((address_space(1))) unsigned int* gp_t;
    typedef __attribute__((address_space(3))) unsigned int* lp_t;
    __builtin_amdgcn_global_load_lds((gp_t)g, (lp_t)l, 16, 0, 0);
}

__device__ __forceinline__ float rl(float v, int l) {   // wave-uniform broadcast (SGPR)
    return __builtin_bit_cast(float, __builtin_amdgcn_readlane(__builtin_bit_cast(int, v), l));
}

// ------------------------------------------------ normalize + cast to bf16
__global__ __launch_bounds__(256) void normcvt_kernel(
    const float* __restrict__ x, const float* __restrict__ y,
    unsigned short* __restrict__ xb, unsigned short* __restrict__ yb)
{
    const int wid = blockIdx.x * 4 + (threadIdx.x >> 6);
    const int lane = threadIdx.x & 63;
    if (wid >= XROWS + YROWS) return;
    const float* src;
    unsigned short* dst;
    if (wid < XROWS) { src = x + (size_t)wid * HD;           dst = xb + (size_t)wid * HD; }
    else             { src = y + (size_t)(wid - XROWS) * HD; dst = yb + (size_t)(wid - XROWS) * HD; }
    const float4 v0 = *(const float4*)(src + lane * 8);
    const float4 v1 = *(const float4*)(src + lane * 8 + 4);
    float s = v0.x*v0.x + v0.y*v0.y + v0.z*v0.z + v0.w*v0.w
            + v1.x*v1.x + v1.y*v1.y + v1.z*v1.z + v1.w*v1.w;
    #pragma unroll
    for (int o = 32; o > 0; o >>= 1) s += __shfl_xor(s, o, 64);
    const float inv = 1.0f / fmaxf(sqrtf(s), 1e-12f);
    short8 ov;
    ov[0] = (short)f2bf(v0.x * inv); ov[1] = (short)f2bf(v0.y * inv);
    ov[2] = (short)f2bf(v0.z * inv); ov[3] = (short)f2bf(v0.w * inv);
    ov[4] = (short)f2bf(v1.x * inv); ov[5] = (short)f2bf(v1.y * inv);
    ov[6] = (short)f2bf(v1.z * inv); ov[7] = (short)f2bf(v1.w * inv);
    *(short8*)(dst + lane * 8) = ov;
}

// ------------------------------------------------ bf16 MFMA GEMM
// C[12544 x 2048] = Xb * Yb^T, scattered into d_out at ((i*64+j)*1650 + p*32+l)
#define BM 128
#define BN 128
#define BK 32

__global__ __launch_bounds__(256) void mfma_gemm_kernel(
    const unsigned short* __restrict__ xb, const unsigned short* __restrict__ yb,
    float* __restrict__ outS)
{
    __shared__ unsigned short lA[BM * BK];   // 8 KB, row-major [128][32]
    __shared__ unsigned short lB[BN * BK];   // 8 KB, row-major [128][32]
    const int tid  = threadIdx.x;
    const int lane = tid & 63;
    const int wv   = tid >> 6;          // wave 0..3
    const int wr   = wv >> 1, wc = wv & 1;
    const int mblk = blockIdx.x >> 4;   // 0..97
    const int nblk = blockIdx.x & 15;   // fastest -> A-tile L2 reuse
    const int m0 = mblk * BM, n0 = nblk * BN;

    floatx4 acc[4][4] = {};

    const int srow = tid >> 2;          // 0..63 (staging row within pass)
    const int skq  = (tid & 3) * 8;     // k offset, 8 bf16 = 16 B

    for (int kt = 0; kt < HD / BK; ++kt) {
        const int k0 = kt * BK;
        __syncthreads();                 // previous compute done before overwrite
        gload_lds16(xb + (size_t)(m0 +      srow) * HD + k0 + skq, (char*)lA +        wv * 1024);
        gload_lds16(xb + (size_t)(m0 + 64 + srow) * HD + k0 + skq, (char*)lA + 4096 + wv * 1024);
        gload_lds16(yb + (size_t)(n0 +      srow) * HD + k0 + skq, (char*)lB +        wv * 1024);
        gload_lds16(yb + (size_t)(n0 + 64 + srow) * HD + k0 + skq, (char*)lB + 4096 + wv * 1024);
        __syncthreads();                 // compiler drains vmcnt(0) here

        const int krow = (lane >> 4) * 8;
        short8 aF[4], bF[4];
        #pragma unroll
        for (int mi = 0; mi < 4; ++mi)
            aF[mi] = *(const short8*)&lA[(wr * 64 + mi * 16 + (lane & 15)) * BK + krow];
        #pragma unroll
        for (int ni = 0; ni < 4; ++ni)
            bF[ni] = *(const short8*)&lB[(wc * 64 + ni * 16 + (lane & 15)) * BK + krow];
        #pragma unroll
        for (int mi = 0; mi < 4; ++mi)
            #pragma unroll
            for (int ni = 0; ni < 4; ++ni)
                acc[mi][ni] = __builtin_amdgcn_mfma_f32_16x16x32_bf16(
                    aF[mi], bF[ni], acc[mi][ni], 0, 0, 0);
    }

    // epilogue: C/D layout col=lane&15, row=(lane>>4)*4+q  (m89-verified)
    #pragma unroll
    for (int mi = 0; mi < 4; ++mi) {
        #pragma unroll
        for (int q = 0; q < 4; ++q) {
            const int r = m0 + wr * 64 + mi * 16 + (lane >> 4) * 4 + q;
            const int i = r / NM;
            const int p = r - i * NM;
            #pragma unroll
            for (int ni = 0; ni < 4; ++ni) {
                const int c = n0 + wc * 64 + ni * 16 + (lane & 15);
                const int j = c >> 5, lc = c & 31;
                outS[(size_t)(i * 64 + j) * BSTRIDE + p * 32 + lc] = acc[mi][ni][q];
            }
        }
    }
}

// ---------------------------------------------------------------- sinkhorn: one wave per pair
// Multiplicative form, fully register-resident: lane p holds K row p (33 VGPR),
// lane l holds K col l (50 VGPR, via one-time LDS transpose). Broadcasts via
// v_readlane -> SGPR. Inner loop: zero LDS ops, zero barriers.
__global__ __launch_bounds__(256) void sinkhorn_kernel(
    float* __restrict__ outZ,
    const int* __restrict__ ymask,
    const float* __restrict__ d_im, const float* __restrict__ d_lang,
    float* __restrict__ scores2)
{
    const int wv   = threadIdx.x >> 6;     // wave 0..3, each owns one pair
    const int lane = threadIdx.x & 63;
    const int b = blockIdx.x * 4 + wv;
    const int j = b & 63;
    __shared__ float sZall[4][1684];       // per-wave scratch (transpose, then Zm staging)
    float* zs = sZall[wv];
    float* base = outZ + (size_t)b * BSTRIDE;

    const int mval = (lane < NL) ? (ymask[j * NL + lane] != 0) : 1;
    const unsigned long long vb = __ballot(lane < NL && !mval);  // bit c = col c valid
    const float ns = (float)__popcll(vb);
    const float kim   = __expf(fminf(fmaxf(d_im[0],   -1.f), 1.f) * INVREG);
    const float klang = __expf(fminf(fmaxf(d_lang[0], -1.f), 1.f) * INVREG);

    // ---- build K row in registers ----
    float kr[33];
    #pragma unroll
    for (int c = 0; c < 33; ++c) kr[c] = 0.f;
    if (lane < NM) {
        #pragma unroll
        for (int h = 0; h < 16; ++h) {     // float2: base is only 8B-aligned
            const float2 v = *(const float2*)(base + lane * NL + h * 2);
            kr[h*2]   = ((vb >> (h*2))   & 1ull) ? __expf(v.x * INVREG) : 0.f;
            kr[h*2+1] = ((vb >> (h*2+1)) & 1ull) ? __expf(v.y * INVREG) : 0.f;
        }
    } else if (lane == NM) {               // dustbin row p=49
        #pragma unroll
        for (int c = 0; c < NL; ++c) kr[c] = ((vb >> c) & 1ull) ? klang : 0.f;
    }
    kr[32] = kim;

    // ---- one-time transpose to get K col in registers (lanes 0..32) ----
    if (lane < MP1) {
        #pragma unroll
        for (int c = 0; c < 33; ++c) zs[c * 51 + lane] = kr[c];
    }
    asm volatile("s_waitcnt lgkmcnt(0)" ::: "memory");
    __builtin_amdgcn_sched_barrier(0);
    float kc[50];
    #pragma unroll
    for (int p = 0; p < 50; ++p) kc[p] = 0.f;
    if (lane < LP1) {
        #pragma unroll
        for (int p = 0; p < 50; ++p) kc[p] = zs[lane * 51 + p];
    }

    const float mup = (lane < NM) ? 1.f : ns;     // lane 49 -> ns
    const float nup = (lane < NL) ? 1.f : 49.f;   // lane 32 -> m
    const bool colA = (lane < NL) ? (((vb >> lane) & 1ull) != 0ull) : (lane == NL);
    float eu = 0.f;
    float ev = colA ? 1.f : 0.f;

    // ---- 10 iterations, pure VALU/SALU ----
    for (int it = 0; it < 10; ++it) {
        float a0 = 0.f, a1 = 0.f, a2 = 0.f, a3 = 0.f;
        #pragma unroll
        for (int c = 0; c < 33; c += 4) {
            a0 = fmaf(kr[c], rl(ev, c), a0);
            if (c + 1 < 33) a1 = fmaf(kr[c+1], rl(ev, c+1), a1);
            if (c + 2 < 33) a2 = fmaf(kr[c+2], rl(ev, c+2), a2);
            if (c + 3 < 33) a3 = fmaf(kr[c+3], rl(ev, c+3), a3);
        }
        eu = __fdividef(mup, (a0 + a1) + (a2 + a3));

        a0 = a1 = a2 = a3 = 0.f;
        #pragma unroll
        for (int p = 0; p < 50; p += 4) {
            a0 = fmaf(kc[p], rl(eu, p), a0);
            if (p + 1 < 50) a1 = fmaf(kc[p+1], rl(eu, p+1), a1);
            if (p + 2 < 50) a2 = fmaf(kc[p+2], rl(eu, p+2), a2);
            if (p + 3 < 50) a3 = fmaf(kc[p+3], rl(eu, p+3), a3);
        }
        const float Sv = (a0 + a1) + (a2 + a3);
        ev = colA ? __fdividef(nup, Sv) : 0.f;
    }

    // ---- epilogue: Zm = K*eu*ev staged to LDS; ot from lnK (= score/TEMP) ----
    float ot = 0.f;
    if (lane < MP1) {
        #pragma unroll
        for (int c = 0; c < 33; ++c) {
            const float zm = kr[c] * eu * rl(ev, c);
            zs[lane * 33 + c] = zm;
            if (lane < NM && c < NL && kr[c] > 0.f)
                ot = fmaf(__logf(kr[c]), zm, ot);   // lnK = 10*score = score/TEMP
        }
    }
    #pragma unroll
    for (int o = 32; o > 0; o >>= 1) ot += __shfl_xor(ot, o, 64);
    if (lane == 0) scores2[b] = ot;
    asm volatile("s_waitcnt lgkmcnt(0)" ::: "memory");
    __builtin_amdgcn_sched_barrier(0);
    // coalesced writeback: 1650 floats = 825 float2
    #pragma unroll
    for (int t = 0; t < 13; ++t) {
        const int idx = t * 64 + lane;
        if (idx < 825) *(float2*)(base + idx * 2) = *(const float2*)&zs[idx * 2];
    }
}

// ---------------------------------------------------------------- InfoNCE loss
__global__ __launch_bounds__(256) void loss_kernel(
    const float* __restrict__ s2, float* __restrict__ out)
{
    const int i = threadIdx.x;
    const int g = i >> 2;
    const float pos = s2[i * 64 + g];
    float mx = -3.0e38f;
    for (int jj = 0; jj < 64; ++jj) mx = fmaxf(mx, s2[i * 64 + jj]);
    float sm = 0.f;
    for (int jj = 0; jj < 64; ++jj) sm += __expf(s2[i * 64 + jj] - mx);
    const float lse1 = __logf(sm) + mx;

    float mx2 = -3.0e38f;
    for (int k = 0; k < 256; ++k) {
        const bool allowed = ((k >> 2) != g) || (k == i);
        if (allowed) mx2 = fmaxf(mx2, s2[k * 64 + g]);
    }
    float sm2 = 0.f;
    for (int k = 0; k < 256; ++k) {
        const bool allowed = ((k >> 2) != g) || (k == i);
        if (allowed) sm2 += __expf(s2[k * 64 + g] - mx2);
    }
    const float lse2 = __logf(sm2) + mx2;

    float li = 0.5f * (lse1 - pos) + 0.5f * (lse2 - pos);
    #pragma unroll
    for (int o = 32; o > 0; o >>= 1) li += __shfl_xor(li, o, 64);
    __shared__ float wred[4];
    if ((i & 63) == 0) wred[i >> 6] = li;
    __syncthreads();
    if (i == 0) out[0] = (wred[0] + wred[1] + wred[2] + wred[3]) * (1.0f / 256.0f);
}

// ---------------------------------------------------------------- launch
extern "C" void kernel_launch(void* const* d_in, const int* in_sizes, int n_in,
                              void* d_out, int out_size, void* d_ws, size_t ws_size,
                              hipStream_t stream)
{
    const float* x      = (const float*)d_in[0];
    const float* y      = (const float*)d_in[1];
    const float* d_im   = (const float*)d_in[2];
    const float* d_lang = (const float*)d_in[3];
    const int* ymask    = (const int*)d_in[4];
    float* out = (float*)d_out;
    float* ws  = (float*)d_ws;

    float* s2          = ws;                                  // 16384 floats
    unsigned short* xb = (unsigned short*)(ws + 16384);       // 12544*512 bf16
    unsigned short* yb = xb + (size_t)XROWS * HD;             // 2048*512 bf16

    normcvt_kernel<<<(XROWS + YROWS + 3) / 4, 256, 0, stream>>>(x, y, xb, yb);
    mfma_gemm_kernel<<<(XROWS / BM) * (YROWS / BN), 256, 0, stream>>>(xb, yb, out);
    sinkhorn_kernel<<<4096, 256, 0, stream>>>(out, ymask, d_im, d_lang, s2);
    loss_kernel<<<1, 256, 0, stream>>>(s2, out + (size_t)16384 * BSTRIDE);
}